// Round 1
// 552.913 us; speedup vs baseline: 1.2077x; 1.2077x over previous
//
#include <hip/hip_runtime.h>
#include <hip/hip_bf16.h>

#define BB 64
#define KN 64
#define NPTS 32768
#define DD 2048
#define NCC 2048
#define NH 512
#define MM 4096   /* BB*KN */
#define K2 4096   /* 2*DD  */

typedef unsigned short u16;
typedef unsigned int u32;
typedef __attribute__((ext_vector_type(8))) short short8;
typedef __attribute__((ext_vector_type(4))) float f32x4;

__device__ __forceinline__ float bf2f(u32 u){
  union { u32 i; float f; } v; v.i = u << 16; return v.f;
}
__device__ __forceinline__ u16 f2bf(float f){
  union { float f; u32 i; } v; v.f = f;
  u32 x = v.i;
  return (u16)((x + 0x7fffu + ((x >> 16) & 1u)) >> 16);
}

// global_load_lds: per-lane global src, wave-uniform LDS base (+lane*16 by HW)
typedef __attribute__((address_space(3))) u32 as3_u32;
typedef const __attribute__((address_space(1))) u32 as1_u32;
__device__ __forceinline__ void glds16(const void* g, void* l){
  __builtin_amdgcn_global_load_lds((as1_u32*)g, (as3_u32*)l, 16, 0, 0);
}

// ---------------- runtime dtype detection ----------------
__global__ void k_dtype(const u32* __restrict__ w, int* __restrict__ flag){
  __shared__ int cnt;
  if(threadIdx.x==0) cnt = 0;
  __syncthreads();
  int c = 0;
  for(int i=threadIdx.x; i<1024; i+=256){
    u32 e = (w[i] >> 7) & 0xffu;
    c += (e >= 110 && e <= 135) ? 1 : 0;
  }
  atomicAdd(&cnt, c);
  __syncthreads();
  if(threadIdx.x==0) *flag = (cnt < 512) ? 1 : 0;   // 1 = inputs are float32
}

// ---------------- cluster means via counting sort ----------------
__global__ void k_count(const int* __restrict__ labels, int* __restrict__ counts){
  int n = blockIdx.x*256 + threadIdx.x;
  atomicAdd(&counts[labels[n]], 1);
}

__global__ void k_scan(const int* __restrict__ counts, int* __restrict__ offsets){
  __shared__ int sb[256];
  int t = threadIdx.x;
  int c[8]; int s = 0;
  #pragma unroll
  for(int i=0;i<8;i++){ c[i] = counts[t*8+i]; s += c[i]; }
  sb[t] = s; __syncthreads();
  int v = s;
  for(int off=1; off<256; off<<=1){
    int u = (t>=off) ? sb[t-off] : 0;
    __syncthreads();
    v += u; sb[t] = v;
    __syncthreads();
  }
  int run = v - s;
  #pragma unroll
  for(int i=0;i<8;i++){ offsets[t*8+i] = run; run += c[i]; }
}

__global__ void k_scatter(const int* __restrict__ labels, const int* __restrict__ offsets,
                          int* __restrict__ cursor, int* __restrict__ sorted){
  int n = blockIdx.x*256 + threadIdx.x;
  int c = labels[n];
  int p = atomicAdd(&cursor[c], 1);
  sorted[offsets[c] + p] = n;
}

__global__ __launch_bounds__(256) void k_clumean(
    const void* __restrict__ feat, const int* __restrict__ counts,
    const int* __restrict__ offsets, const int* __restrict__ sorted,
    const int* __restrict__ dflag, float* __restrict__ clu){
  int c = blockIdx.x, t = threadIdx.x;
  int isf32 = *dflag;
  int cnt = counts[c], start = offsets[c];
  float acc[8] = {0,0,0,0,0,0,0,0};
  if(isf32){
    const float* ff = (const float*)feat;
    for(int r=0; r<cnt; r++){
      int row = sorted[start+r];
      const float4* p = (const float4*)(ff + (size_t)row*DD + t*8);
      float4 a = p[0], b = p[1];
      acc[0]+=a.x; acc[1]+=a.y; acc[2]+=a.z; acc[3]+=a.w;
      acc[4]+=b.x; acc[5]+=b.y; acc[6]+=b.z; acc[7]+=b.w;
    }
  } else {
    const u16* fb = (const u16*)feat;
    for(int r=0; r<cnt; r++){
      int row = sorted[start+r];
      uint4 v = *(const uint4*)(fb + (size_t)row*DD + t*8);
      acc[0]+=bf2f(v.x&0xffffu); acc[1]+=bf2f(v.x>>16);
      acc[2]+=bf2f(v.y&0xffffu); acc[3]+=bf2f(v.y>>16);
      acc[4]+=bf2f(v.z&0xffffu); acc[5]+=bf2f(v.z>>16);
      acc[6]+=bf2f(v.w&0xffffu); acc[7]+=bf2f(v.w>>16);
    }
  }
  float div = fmaxf((float)cnt, 1.0f);
  float* o = clu + (size_t)c*DD + t*8;
  #pragma unroll
  for(int i=0;i<8;i++) o[i] = acc[i] / div;
}

// ---------------- per-sample meta: labels of neighbors, keep mask ----------------
__global__ __launch_bounds__(64) void k_meta(
    const int* __restrict__ labels, const int* __restrict__ knn,
    int* __restrict__ lab_ws, int* __restrict__ keep_ws){
  int b = blockIdx.x, t = threadIdx.x;
  __shared__ int sl[64];
  int nbr = knn[b*64 + t];
  int lab = labels[nbr];
  sl[t] = lab; __syncthreads();
  int dup = 0;
  for(int j=0;j<t;j++) dup |= (sl[j]==lab);
  lab_ws[b*64+t] = lab;
  keep_ws[b*64+t] = dup ? 0 : 1;
}

// ---------------- partial A: block (b, dgroup g) accumulates 512 dims ----------------
__global__ __launch_bounds__(256) void k_Apart(
    const void* __restrict__ feat, const float* __restrict__ clu,
    const int* __restrict__ indexes, const int* __restrict__ lab_ws,
    const int* __restrict__ dflag, float* __restrict__ Apart){
  int b = blockIdx.x >> 2, g = blockIdx.x & 3;
  int t = threadIdx.x;
  __shared__ float cfT[64][68];
  __shared__ int sl[64];
  int isf32 = *dflag;
  if(t < 64) sl[t] = lab_ws[b*64 + t];
  int qidx = indexes[b];
  __syncthreads();

  int i0 = (t & 15)*4, j0 = (t >> 4)*4;
  float acc[4][4];
  #pragma unroll
  for(int a=0;a<4;a++)
    #pragma unroll
    for(int c2=0;c2<4;c2++) acc[a][c2] = 0.f;

  for(int ch=g*8; ch<g*8+8; ch++){
    int dbase = ch*64;
    #pragma unroll
    for(int ps=0; ps<16; ps++){
      int idx = ps*256 + t;
      int k = idx >> 6, dd = idx & 63;
      float v;
      if(k == 0){
        size_t fi = (size_t)qidx*DD + dbase + dd;
        v = isf32 ? ((const float*)feat)[fi] : bf2f(((const u16*)feat)[fi]);
      } else {
        v = clu[(size_t)sl[k]*DD + dbase + dd];
      }
      cfT[dd][k] = v;
    }
    __syncthreads();
    #pragma unroll 4
    for(int dd=0; dd<64; dd++){
      float4 av = *(const float4*)&cfT[dd][i0];
      float4 bv = *(const float4*)&cfT[dd][j0];
      float aa[4] = {av.x, av.y, av.z, av.w};
      float bbv[4] = {bv.x, bv.y, bv.z, bv.w};
      #pragma unroll
      for(int ii=0;ii<4;ii++)
        #pragma unroll
        for(int jj=0;jj<4;jj++)
          acc[ii][jj] += aa[ii]*bbv[jj];
    }
    __syncthreads();
  }

  float* op = Apart + ((size_t)(g*64 + b))*4096;
  #pragma unroll
  for(int ii=0;ii<4;ii++)
    *(float4*)&op[(i0+ii)*64 + j0] = make_float4(acc[ii][0], acc[ii][1], acc[ii][2], acc[ii][3]);
}

// ---------------- final A: sum partials, top-5 mask (padded LDS), norms, adj ----------------
__global__ __launch_bounds__(256) void k_Afinal(
    const float* __restrict__ Apart, const int* __restrict__ keep_ws,
    float* __restrict__ adj, float* __restrict__ norms){
  int b = blockIdx.x, t = threadIdx.x;
  __shared__ float A[64][65];
  __shared__ unsigned long long mb[64];
  __shared__ int sk[64];
  const float* P = Apart + (size_t)b*4096;
  const size_t gs = (size_t)64*4096;
  #pragma unroll
  for(int ps=0; ps<16; ps++){
    int idx = ps*256 + t;
    float s = P[idx] + P[idx+gs] + P[idx+2*gs] + P[idx+3*gs];
    A[idx>>6][idx&63] = s * 0.2f;
  }
  __syncthreads();
  if(t < 64){
    unsigned long long chosen = 0;
    const float* row = A[t];
    #pragma unroll
    for(int p=0;p<5;p++){
      float best = -INFINITY; int bi = 0;
      for(int j=0;j<64;j++){
        bool taken = (chosen >> j) & 1ull;
        float v = row[j];
        if(!taken && v > best){ best = v; bi = j; }
      }
      chosen |= (1ull << bi);
    }
    mb[t] = chosen;
    sk[t] = keep_ws[b*64+t];
    norms[b*64+t] = sqrtf(fmaxf(A[t][t]*5.0f, 0.0f));
  }
  __syncthreads();
  float* O = adj + (size_t)b*4096;
  #pragma unroll
  for(int ps=0; ps<16; ps++){
    int idx = ps*256 + t;
    int i = idx >> 6, j = idx & 63;
    bool on = ((mb[i]>>j)&1ull) && ((mb[j]>>i)&1ull) && sk[i] && sk[j];
    O[idx] = on ? A[i][j] : 0.0f;
  }
}

// ---------------- x rows: one block per (b,k); normalize, center, emit bf16 ----------------
__global__ __launch_bounds__(256) void k_xrow(
    const void* __restrict__ feat, const float* __restrict__ clu,
    const int* __restrict__ indexes, const int* __restrict__ lab_ws,
    const float* __restrict__ norms, const int* __restrict__ dflag,
    u16* __restrict__ xab){
  int r = blockIdx.x, t = threadIdx.x;
  int b = r >> 6, k = r & 63;
  size_t obase = (size_t)r*K2 + t*8;
  if(k == 0){
    *(uint4*)(xab + obase) = make_uint4(0,0,0,0);   // row 0: cf - cf[0] == 0
    return;
  }
  int isf32 = *dflag;
  int qidx = indexes[b];
  float inv0 = 1.0f / fmaxf(norms[b*64], 1e-30f);
  float invk = 1.0f / fmaxf(norms[r], 1e-30f);
  float q[8];
  if(isf32){
    const float4* qp = (const float4*)((const float*)feat + (size_t)qidx*DD + t*8);
    float4 a = qp[0], bq = qp[1];
    q[0]=a.x; q[1]=a.y; q[2]=a.z; q[3]=a.w; q[4]=bq.x; q[5]=bq.y; q[6]=bq.z; q[7]=bq.w;
  } else {
    uint4 v = *(const uint4*)((const u16*)feat + (size_t)qidx*DD + t*8);
    q[0]=bf2f(v.x&0xffffu); q[1]=bf2f(v.x>>16);
    q[2]=bf2f(v.y&0xffffu); q[3]=bf2f(v.y>>16);
    q[4]=bf2f(v.z&0xffffu); q[5]=bf2f(v.z>>16);
    q[6]=bf2f(v.w&0xffffu); q[7]=bf2f(v.w>>16);
  }
  const float* cp = clu + (size_t)lab_ws[r]*DD + t*8;
  float4 c0 = *(const float4*)cp, c1 = *(const float4*)(cp+4);
  float cv[8] = {c0.x,c0.y,c0.z,c0.w,c1.x,c1.y,c1.z,c1.w};
  u16 ob[8];
  #pragma unroll
  for(int e=0;e<8;e++) ob[e] = f2bf(cv[e]*invk - q[e]*inv0);
  uint4 w;
  w.x = (u32)ob[0] | ((u32)ob[1]<<16);
  w.y = (u32)ob[2] | ((u32)ob[3]<<16);
  w.z = (u32)ob[4] | ((u32)ob[5]<<16);
  w.w = (u32)ob[6] | ((u32)ob[7]<<16);
  *(uint4*)(xab + obase) = w;
}

// ---------------- agg = adj @ x, write bf16 into cols [2048,4096) ----------------
__global__ __launch_bounds__(256) void k_agg(
    const float* __restrict__ adj, u16* __restrict__ xab){
  int r = blockIdx.x, t = threadIdx.x; int b = r >> 6;
  __shared__ float arow[64];
  if(t < 64) arow[t] = adj[(size_t)r*64 + t];
  __syncthreads();
  float acc[8] = {0,0,0,0,0,0,0,0};
  int d = t*8;
  for(int j=0;j<64;j++){
    float s = arow[j];
    if(s != 0.0f){
      const u16* xp = xab + (size_t)(b*64+j)*K2 + d;
      uint4 v = *(const uint4*)xp;
      acc[0]+=s*bf2f(v.x&0xffffu); acc[1]+=s*bf2f(v.x>>16);
      acc[2]+=s*bf2f(v.y&0xffffu); acc[3]+=s*bf2f(v.y>>16);
      acc[4]+=s*bf2f(v.z&0xffffu); acc[5]+=s*bf2f(v.z>>16);
      acc[6]+=s*bf2f(v.w&0xffffu); acc[7]+=s*bf2f(v.w>>16);
    }
  }
  u16* o = xab + (size_t)r*K2 + DD + d;
  #pragma unroll
  for(int e=0;e<8;e++) o[e] = f2bf(acc[e]);
}

// ---------------- transpose + normalize weights to bf16 ([Kd,Nd] -> [Nd,Kd]) ----------------
__global__ __launch_bounds__(256) void k_transpose(
    const void* __restrict__ src, u16* __restrict__ dst, int Kd, int Nd,
    const int* __restrict__ dflag){
  __shared__ u16 tile[64][65];
  int isf32 = *dflag;
  int nbt = Nd >> 6;
  int k0 = (blockIdx.x / nbt) << 6;
  int n0 = (blockIdx.x % nbt) << 6;
  int t = threadIdx.x;
  if(isf32){
    const float* s = (const float*)src;
    #pragma unroll
    for(int ph=0; ph<16; ph++){
      int idx = ph*256 + t;
      int r = idx >> 6, c = idx & 63;
      tile[r][c] = f2bf(s[(size_t)(k0+r)*Nd + n0 + c]);
    }
  } else {
    const u16* s = (const u16*)src;
    #pragma unroll
    for(int ph=0; ph<16; ph++){
      int idx = ph*256 + t;
      int r = idx >> 6, c = idx & 63;
      tile[r][c] = s[(size_t)(k0+r)*Nd + n0 + c];
    }
  }
  __syncthreads();
  #pragma unroll
  for(int ph=0; ph<16; ph++){
    int idx = ph*256 + t;
    int r = idx >> 6, c = idx & 63;
    dst[(size_t)(n0+r)*Kd + k0 + c] = tile[c][r];
  }
}

// ---------------- bf16 MFMA GEMM: C = epi(A @ Bt^T + bias)  (Bt is [Nd,Kd]) ----------------
// BM=128, BN=64, BK=64, 256 threads (4 waves, 2x2), global_load_lds staging,
// T2 XOR swizzle (source-side + read-side), 2-phase double-buffer pipeline,
// XCD-chunked block swizzle. grid = (Md/128)*(Nd/64), must be %8==0.
template<int EPI>
__global__ __launch_bounds__(256) void k_gemm(
    const u16* __restrict__ Am, const u16* __restrict__ Bt,
    const void* __restrict__ bias, const void* __restrict__ pa,
    const int* __restrict__ dflag,
    void* __restrict__ Cout, int Md, int Nd, int Kd)
{
  __shared__ u16 As[2][128*64];
  __shared__ u16 Bs[2][64*64];
  int isf32 = *dflag;
  int t = threadIdx.x;
  int nblk = gridDim.x;
  int bid = (blockIdx.x & 7)*(nblk >> 3) + (blockIdx.x >> 3);  // XCD chunking
  int nb = Nd >> 6;
  int m0 = (bid / nb) << 7;
  int n0 = (bid % nb) << 6;
  int wave = t >> 6, lane = t & 63;
  int wm = wave >> 1, wn = wave & 1;
  int lm = lane & 15, lq = lane >> 4;
  int lrow = lane >> 3, lcol = lane & 7;

  f32x4 acc[4][2];
  #pragma unroll
  for(int i=0;i<4;i++)
    #pragma unroll
    for(int j=0;j<2;j++) acc[i][j] = (f32x4){0.f,0.f,0.f,0.f};

  // stage one 128x64 A-tile + 64x64 B-tile into buffer `buf`.
  // LDS layout: linear [row][64], 128B rows; logical 16B-chunk q lives at
  // physical chunk p = q ^ (row&7). glds writes lane l at base+16*l, so the
  // SOURCE address carries the inverse swizzle: col = lcol ^ (row&7).
  auto stage = [&](int buf, int kb){
    #pragma unroll
    for(int c=0;c<4;c++){
      int ch = wave*4 + c;            // 16 chunks of 8 rows (A)
      int row = ch*8 + lrow;
      int col = lcol ^ (row & 7);
      glds16(Am + (size_t)(m0+row)*Kd + kb + col*8, &As[buf][ch*512]);
    }
    #pragma unroll
    for(int c=0;c<2;c++){
      int ch = wave*2 + c;            // 8 chunks of 8 rows (B)
      int row = ch*8 + lrow;
      int col = lcol ^ (row & 7);
      glds16(Bt + (size_t)(n0+row)*Kd + kb + col*8, &Bs[buf][ch*512]);
    }
  };

  stage(0, 0);
  __syncthreads();
  int cur = 0;
  for(int kb=0; kb<Kd; kb+=64){
    if(kb + 64 < Kd) stage(cur^1, kb+64);   // prefetch next tile (in flight across compute)
    #pragma unroll
    for(int kk=0;kk<2;kk++){
      short8 af[4], bfr[2];
      #pragma unroll
      for(int mi=0;mi<4;mi++){
        int r = wm*64 + mi*16 + lm;
        int p = ((kk<<2)+lq) ^ (r & 7);
        union{ uint4 u; short8 v; } x;
        x.u = *(const uint4*)&As[cur][r*64 + p*8];
        af[mi] = x.v;
      }
      #pragma unroll
      for(int ni=0;ni<2;ni++){
        int r = wn*32 + ni*16 + lm;
        int p = ((kk<<2)+lq) ^ (r & 7);
        union{ uint4 u; short8 v; } x;
        x.u = *(const uint4*)&Bs[cur][r*64 + p*8];
        bfr[ni] = x.v;
      }
      #pragma unroll
      for(int mi=0;mi<4;mi++)
        #pragma unroll
        for(int ni=0;ni<2;ni++)
          acc[mi][ni] = __builtin_amdgcn_mfma_f32_16x16x32_bf16(af[mi], bfr[ni], acc[mi][ni], 0, 0, 0);
    }
    __syncthreads();   // drains vmcnt (prefetch landed) + lgkmcnt (ds_reads done)
    cur ^= 1;
  }

  #pragma unroll
  for(int ni=0;ni<2;ni++){
    int col = n0 + wn*32 + ni*16 + lm;
    float bs = isf32 ? ((const float*)bias)[col] : bf2f(((const u16*)bias)[col]);
    float av = 0.f;
    if(EPI==1) av = isf32 ? ((const float*)pa)[col] : bf2f(((const u16*)pa)[col]);
    #pragma unroll
    for(int mi=0;mi<4;mi++){
      int rowb = m0 + wm*64 + mi*16 + lq*4;
      #pragma unroll
      for(int r2=0;r2<4;r2++){
        float v = acc[mi][ni][r2] + bs;
        if(EPI==0){
          v = fmaxf(v, 0.f);
          ((u16*)Cout)[(size_t)(rowb+r2)*Nd + col] = f2bf(v);
        } else {
          v = (v > 0.f) ? v : av*v;
          ((float*)Cout)[(size_t)(rowb+r2)*Nd + col] = v;
        }
      }
    }
  }
}

// ---------------- final: logits = h1 @ w2 + b2, softmax over 2 ----------------
__global__ __launch_bounds__(256) void k_out(
    const float* __restrict__ h1, const void* __restrict__ w2,
    const void* __restrict__ b2, const int* __restrict__ dflag,
    void* __restrict__ out){
  int t = threadIdx.x; int lane = t & 63; int row = blockIdx.x*4 + (t >> 6);
  int isf32 = *dflag;
  const float* hr = h1 + (size_t)row*NH;
  float s0 = 0.f, s1 = 0.f;
  #pragma unroll
  for(int j=0;j<NH/64;j++){
    int i = lane + j*64;
    float h = hr[i];
    float w0 = isf32 ? ((const float*)w2)[i*2+0] : bf2f(((const u16*)w2)[i*2+0]);
    float w1v= isf32 ? ((const float*)w2)[i*2+1] : bf2f(((const u16*)w2)[i*2+1]);
    s0 += h * w0;
    s1 += h * w1v;
  }
  #pragma unroll
  for(int off=32; off>0; off>>=1){
    s0 += __shfl_down(s0, off);
    s1 += __shfl_down(s1, off);
  }
  if(lane==0){
    float bb0 = isf32 ? ((const float*)b2)[0] : bf2f(((const u16*)b2)[0]);
    float bb1 = isf32 ? ((const float*)b2)[1] : bf2f(((const u16*)b2)[1]);
    float l0 = s0 + bb0;
    float l1 = s1 + bb1;
    float m = fmaxf(l0, l1);
    float e0 = expf(l0 - m), e1 = expf(l1 - m);
    float inv = 1.0f / (e0 + e1);
    if(isf32){
      ((float*)out)[row*2+0] = e0*inv;
      ((float*)out)[row*2+1] = e1*inv;
    } else {
      ((u16*)out)[row*2+0] = f2bf(e0*inv);
      ((u16*)out)[row*2+1] = f2bf(e1*inv);
    }
  }
}

// ---------------- diagnostic sentinel: ws too small (~3.0 in either dtype) ----------------
__global__ void k_fill_sentinel(u32* __restrict__ out, int nwords){
  int i = blockIdx.x*256 + threadIdx.x;
  if(i < nwords) out[i] = 0x40404040u;
}

extern "C" void kernel_launch(void* const* d_in, const int* in_sizes, int n_in,
                              void* d_out, int out_size, void* d_ws, size_t ws_size,
                              hipStream_t stream) {
  const int* indexes = (const int*)d_in[0];
  const void* feat   = d_in[1];
  const int* labels  = (const int*)d_in[2];
  const int* knn     = (const int*)d_in[3];
  const void* conv_w = d_in[4];
  const void* conv_b = d_in[5];
  const void* w1     = d_in[6];
  const void* b1     = d_in[7];
  const void* pa     = d_in[8];
  const void* w2     = d_in[9];
  const void* b2     = d_in[10];

  char* w = (char*)d_ws;
  size_t o = 0;
  auto alloc = [&](size_t bytes) -> void* {
    void* p = w + o; o = (o + bytes + 255) & ~(size_t)255; return p;
  };
  int*   dflag   = (int*)  alloc(4);
  int*   counts  = (int*)  alloc((size_t)NCC*4);
  int*   cursor  = (int*)  alloc((size_t)NCC*4);
  int*   offsets = (int*)  alloc((size_t)NCC*4);
  int*   lab_ws  = (int*)  alloc((size_t)MM*4);
  int*   keep_ws = (int*)  alloc((size_t)MM*4);
  int*   sorted  = (int*)  alloc((size_t)NPTS*4);
  float* norms   = (float*)alloc((size_t)MM*4);
  float* adj     = (float*)alloc((size_t)BB*64*64*4);
  float* Apart   = (float*)alloc((size_t)4*BB*64*64*4);  // 4 MB partial A
  float* clu     = (float*)alloc((size_t)NCC*DD*4);   // 16 MB; dead before GEMMs
  u16*   xab     = (u16*)  alloc((size_t)MM*K2*2);    // 32 MB
  u16*   cwT     = (u16*)  alloc((size_t)K2*NH*2);    // 4 MB
  u16*   w1T     = (u16*)  alloc((size_t)NH*NH*2);    // 0.5 MB
  u16*   hb      = (u16*)  clu;                       // alias: 4 MB
  float* h1      = (float*)((char*)clu + (size_t)MM*NH*2); // alias: 8 MB

  size_t NEED = o;
  if(ws_size < NEED){
    int nwords = out_size/2;
    k_fill_sentinel<<<(nwords+255)/256, 256, 0, stream>>>((u32*)d_out, nwords);
    return;
  }

  hipMemsetAsync(counts, 0, (size_t)NCC*4*2, stream);   // counts + cursor

  k_dtype  <<<1, 256, 0, stream>>>((const u32*)feat, dflag);
  k_count  <<<NPTS/256, 256, 0, stream>>>(labels, counts);
  k_scan   <<<1, 256, 0, stream>>>(counts, offsets);
  k_scatter<<<NPTS/256, 256, 0, stream>>>(labels, offsets, cursor, sorted);
  k_clumean<<<NCC, 256, 0, stream>>>(feat, counts, offsets, sorted, dflag, clu);
  k_meta   <<<BB, 64, 0, stream>>>(labels, knn, lab_ws, keep_ws);
  k_Apart  <<<BB*4, 256, 0, stream>>>(feat, clu, indexes, lab_ws, dflag, Apart);
  k_Afinal <<<BB, 256, 0, stream>>>(Apart, keep_ws, adj, norms);
  k_xrow   <<<MM, 256, 0, stream>>>(feat, clu, indexes, lab_ws, norms, dflag, xab);
  k_agg    <<<MM, 256, 0, stream>>>(adj, xab);

  k_transpose<<<(K2/64)*(NH/64), 256, 0, stream>>>(conv_w, cwT, K2, NH, dflag);
  k_transpose<<<(NH/64)*(NH/64), 256, 0, stream>>>(w1, w1T, NH, NH, dflag);

  k_gemm<0><<<(MM/128)*(NH/64), 256, 0, stream>>>(xab, cwT, conv_b, nullptr, dflag, (void*)hb, MM, NH, K2);
  k_gemm<1><<<(MM/128)*(NH/64), 256, 0, stream>>>(hb, w1T, b1, pa, dflag, (void*)h1, MM, NH, NH);

  k_out    <<<MM/4, 256, 0, stream>>>(h1, w2, b2, dflag, d_out);
}